// Round 6
// baseline (406.054 us; speedup 1.0000x reference)
//
#include <hip/hip_runtime.h>
#include <hip/hip_bf16.h>

#define GAT_ALPHA 0.2f

typedef short bf16x8 __attribute__((ext_vector_type(8)));
typedef float f32x4 __attribute__((ext_vector_type(4)));

__device__ __forceinline__ unsigned f2bf_u(float x) {
  union { float f; unsigned u; } v; v.f = x;
  return (v.u + 0x7fffu + ((v.u >> 16) & 1u)) >> 16;  // RNE to bf16
}
__device__ __forceinline__ unsigned short f2bf(float x) { return (unsigned short)f2bf_u(x); }

// ---------------- kernel 0: W (512x256 f32) -> WT bf16 (256x512) ----------
__global__ void k_wt(const float* __restrict__ W, unsigned short* __restrict__ WT) {
  int kb = blockIdx.x * 8;       // 64 blocks
  int f = threadIdx.x;           // 256 threads = one f each
  bf16x8 o;
#pragma unroll
  for (int i = 0; i < 8; ++i) o[i] = (short)f2bf(W[(kb + i) * 256 + f]);
  *reinterpret_cast<bf16x8*>(WT + f * 512 + kb) = o;
}

// ---------------- kernel P: adj (int32 0/1) -> permuted bitmap ------------
// Per row: byte-col j8 (bits j=8*j8..8*j8+7) stored at (j8&3)*64 + (j8>>2),
// so k_gat lane q's bytes for ksteps s=0..63 (j8 = q+4s) are the contiguous
// 64 B at q*64. Grid 2048 x 256 thr = 8 rows/block. Pure HBM stream.
__global__ __launch_bounds__(256) void k_pack(const int* __restrict__ adj,
                                              unsigned char* __restrict__ bm) {
  __shared__ unsigned char sb[2048];
  const int bId = blockIdx.x, t = threadIdx.x;
  const int4* base = reinterpret_cast<const int4*>(adj + (size_t)bId * 8 * 2048);
#pragma unroll
  for (int i = 0; i < 8; ++i) {
    int4 v0 = base[i * 512 + t * 2];
    int4 v1 = base[i * 512 + t * 2 + 1];
    unsigned by = (v0.x != 0)        | ((v0.y != 0) << 1) | ((v0.z != 0) << 2) |
                  ((v0.w != 0) << 3) | ((v1.x != 0) << 4) | ((v1.y != 0) << 5) |
                  ((v1.z != 0) << 6) | ((v1.w != 0) << 7);
    sb[i * 256 + (t & 3) * 64 + (t >> 2)] = (unsigned char)by;
  }
  __syncthreads();
  reinterpret_cast<uint2*>(bm + (size_t)bId * 2048)[t] =
      reinterpret_cast<const uint2*>(sb)[t];
}

// ---------------- kernel 1: WhT = (h@W)^T bf16 [b][f][n], + exp(f1/f2) ----
// Grid 1024 (8 b x 128 node-groups of 16), 256 thr, 4 blocks/CU.
// Wave tile: 64 f x 16 n. h register pipeline depth-3.
__global__ __launch_bounds__(256, 4) void k_gemm1(
    const float* __restrict__ h, const unsigned short* __restrict__ WT,
    const float* __restrict__ avec,
    unsigned short* __restrict__ WhT,
    float* __restrict__ E1p, float* __restrict__ E1n,
    float* __restrict__ E2p, float* __restrict__ E2n)
{
  const int bx = blockIdx.x;
  const int b = bx & 7, ng = bx >> 3;
  const int n0 = ng * 16;
  const int t = threadIdx.x;
  const int lane = t & 63, w = t >> 6;
  const int l15 = lane & 15, q = lane >> 4;

  __shared__ __align__(16) unsigned short Wt[256 * 24];
  __shared__ float f1a[16], f2a[16];
  if (t < 16) { f1a[t] = 0.f; f2a[t] = 0.f; }

  f32x4 acc[4];
#pragma unroll
  for (int i = 0; i < 4; ++i) acc[i] = (f32x4){0.f, 0.f, 0.f, 0.f};

  const unsigned short* wtb = WT + (w * 64 + l15) * 512 + q * 8;
  const float* hrow = h + ((size_t)(b * 2048 + n0 + l15)) * 512 + q * 8;

  float4 hS0[2], hS1[2], hS2[2];
  hS0[0] = *reinterpret_cast<const float4*>(hrow);
  hS0[1] = *reinterpret_cast<const float4*>(hrow + 4);
  hS1[0] = *reinterpret_cast<const float4*>(hrow + 32);
  hS1[1] = *reinterpret_cast<const float4*>(hrow + 36);
  hS2[0] = *reinterpret_cast<const float4*>(hrow + 64);
  hS2[1] = *reinterpret_cast<const float4*>(hrow + 68);

#pragma unroll
  for (int k = 0; k < 16; ++k) {
    bf16x8 af[4];
#pragma unroll
    for (int mt = 0; mt < 4; ++mt)
      af[mt] = *reinterpret_cast<const bf16x8*>(wtb + mt * 16 * 512 + k * 32);
    float4 hN[2];
    if (k < 13) {
      hN[0] = *reinterpret_cast<const float4*>(hrow + (k + 3) * 32);
      hN[1] = *reinterpret_cast<const float4*>(hrow + (k + 3) * 32 + 4);
    }
    bf16x8 bb;
    {
      float4 x0 = hS0[0], x1 = hS0[1];
      bb[0] = (short)f2bf(x0.x); bb[1] = (short)f2bf(x0.y);
      bb[2] = (short)f2bf(x0.z); bb[3] = (short)f2bf(x0.w);
      bb[4] = (short)f2bf(x1.x); bb[5] = (short)f2bf(x1.y);
      bb[6] = (short)f2bf(x1.z); bb[7] = (short)f2bf(x1.w);
    }
#pragma unroll
    for (int mt = 0; mt < 4; ++mt)
      acc[mt] = __builtin_amdgcn_mfma_f32_16x16x32_bf16(af[mt], bb, acc[mt], 0, 0, 0);
    hS0[0] = hS1[0]; hS0[1] = hS1[1];
    hS1[0] = hS2[0]; hS1[1] = hS2[1];
    if (k < 13) { hS2[0] = hN[0]; hS2[1] = hN[1]; }
  }

  float s1 = 0.f, s2 = 0.f;
#pragma unroll
  for (int mt = 0; mt < 4; ++mt) {
#pragma unroll
    for (int r = 0; r < 4; ++r) {
      int f = w * 64 + mt * 16 + q * 4 + r;
      float v = acc[mt][r];
      Wt[f * 24 + l15] = f2bf(v);
      s1 += v * avec[f];
      s2 += v * avec[256 + f];
    }
  }
  s1 += __shfl_xor(s1, 16); s1 += __shfl_xor(s1, 32);
  s2 += __shfl_xor(s2, 16); s2 += __shfl_xor(s2, 32);
  __syncthreads();
  if (q == 0) {
    atomicAdd(&f1a[l15], s1);
    atomicAdd(&f2a[l15], s2);
  }
  {
    uint4 va = *reinterpret_cast<const uint4*>(Wt + t * 24);
    uint4 vb = *reinterpret_cast<const uint4*>(Wt + t * 24 + 8);
    unsigned short* dst = WhT + (size_t)(b * 256 + t) * 2048 + n0;
    *reinterpret_cast<uint4*>(dst) = va;
    *reinterpret_cast<uint4*>(dst + 8) = vb;
  }
  __syncthreads();
  if (t < 16) {
    int n = b * 2048 + n0 + t;
    float f1 = f1a[t], f2 = f2a[t];
    E1p[n] = __expf(f1);
    E1n[n] = __expf(GAT_ALPHA * f1);
    E2p[n] = __expf(f2);
    E2n[n] = __expf(GAT_ALPHA * f2);
  }
}

// build one MFMA A-fragment (8 k-cols of row m) in registers from mask byte
__device__ __forceinline__ bf16x8 build_frag_r(
    unsigned by, float e1p, float e1n,
    float4 epl, float4 eph, float4 enl, float4 enh)
{
  float p0 = (by & 1u)   ? fmaxf(e1p * epl.x, e1n * enl.x) : 0.f;
  float p1 = (by & 2u)   ? fmaxf(e1p * epl.y, e1n * enl.y) : 0.f;
  float p2 = (by & 4u)   ? fmaxf(e1p * epl.z, e1n * enl.z) : 0.f;
  float p3 = (by & 8u)   ? fmaxf(e1p * epl.w, e1n * enl.w) : 0.f;
  float p4 = (by & 16u)  ? fmaxf(e1p * eph.x, e1n * enh.x) : 0.f;
  float p5 = (by & 32u)  ? fmaxf(e1p * eph.y, e1n * enh.y) : 0.f;
  float p6 = (by & 64u)  ? fmaxf(e1p * eph.z, e1n * enh.z) : 0.f;
  float p7 = (by & 128u) ? fmaxf(e1p * eph.w, e1n * enh.w) : 0.f;
  union { unsigned u[4]; bf16x8 v; } pk;
  pk.u[0] = f2bf_u(p0) | (f2bf_u(p1) << 16);
  pk.u[1] = f2bf_u(p2) | (f2bf_u(p3) << 16);
  pk.u[2] = f2bf_u(p4) | (f2bf_u(p5) << 16);
  pk.u[3] = f2bf_u(p6) | (f2bf_u(p7) << 16);
  return pk.v;
}

// ---------------- kernel 2: out = elu(softmax-masked P @ Wh) --------------
// BARRIER-FREE. Grid 1024 = 8 b x 4 f-groups x 32 row-groups; 256 thr =
// 4 waves = 4 row-tiles of 16 (same b, same f-group -> shared B stream, L1).
// Wave: 16 rows x 64 f. A-frags built in registers from bitmap bytes; den
// via a 5th MFMA against ones-B (lands in C-layout, zero shuffles).
__global__ __launch_bounds__(256, 4) void k_gat(
    const unsigned char* __restrict__ bm, const unsigned short* __restrict__ WhT,
    const float* __restrict__ E1p, const float* __restrict__ E1n,
    const float* __restrict__ E2p, const float* __restrict__ E2n,
    float* __restrict__ out)
{
  const int bx = blockIdx.x;
  const int b = bx & 7, fg = (bx >> 3) & 3, rg = bx >> 5;
  const int i0 = rg * 64, f0 = fg * 64;
  const int t = threadIdx.x;
  const int lane = t & 63, w = t >> 6;
  const int m = lane & 15, q = lane >> 4;
  const int row = i0 + w * 16 + m;          // this lane's P row

  // bitmap: lane's 64 mask bytes, register-resident for the whole kernel
  const unsigned char* bmr = bm + ((size_t)(b * 2048 + row)) * 256 + q * 64;
  uint4 bmv0 = *reinterpret_cast<const uint4*>(bmr);
  uint4 bmv1 = *reinterpret_cast<const uint4*>(bmr + 16);
  uint4 bmv2 = *reinterpret_cast<const uint4*>(bmr + 32);
  uint4 bmv3 = *reinterpret_cast<const uint4*>(bmr + 48);

  const float e1p = E1p[b * 2048 + row], e1n = E1n[b * 2048 + row];
  const int e2b = b * 2048 + q * 8;

  f32x4 acc[4], accd;
#pragma unroll
  for (int i = 0; i < 4; ++i) acc[i] = (f32x4){0.f, 0.f, 0.f, 0.f};
  accd = (f32x4){0.f, 0.f, 0.f, 0.f};

  bf16x8 ones;
#pragma unroll
  for (int i = 0; i < 8; ++i) ones[i] = (short)0x3F80;  // bf16 1.0

  const unsigned short* Wb = WhT + (size_t)(b * 256 + f0) * 2048 + q * 8;

  // B(0) preload
  bf16x8 Bc[4], Bn[4];
#pragma unroll
  for (int ct = 0; ct < 4; ++ct)
    Bc[ct] = *reinterpret_cast<const bf16x8*>(Wb + (size_t)(ct * 16 + m) * 2048);

  for (int w4 = 0; w4 < 4; ++w4) {
    uint4 bv = (w4 == 0) ? bmv0 : (w4 == 1) ? bmv1 : (w4 == 2) ? bmv2 : bmv3;
#pragma unroll
    for (int s2 = 0; s2 < 16; ++s2) {
      const int s = w4 * 16 + s2;
      unsigned bw = ((s2 >> 2) == 0) ? bv.x : ((s2 >> 2) == 1) ? bv.y
                  : ((s2 >> 2) == 2) ? bv.z : bv.w;
      unsigned by = (bw >> ((s2 & 3) * 8)) & 0xffu;
      // e2 for this kstep (L1-hot, 16 KB/batch)
      const float* p2p = E2p + e2b + s * 32;
      const float* p2n = E2n + e2b + s * 32;
      float4 epl = *reinterpret_cast<const float4*>(p2p);
      float4 eph = *reinterpret_cast<const float4*>(p2p + 4);
      float4 enl = *reinterpret_cast<const float4*>(p2n);
      float4 enh = *reinterpret_cast<const float4*>(p2n + 4);
      // issue B(s+1) (L1/L2), consumed next kstep
      if (s < 63) {
        const unsigned short* pB = Wb + (s + 1) * 32;
#pragma unroll
        for (int ct = 0; ct < 4; ++ct)
          Bn[ct] = *reinterpret_cast<const bf16x8*>(pB + (size_t)(ct * 16 + m) * 2048);
      }
      // A-frag in registers, then 4 num-MFMAs + 1 den-MFMA
      bf16x8 af = build_frag_r(by, e1p, e1n, epl, eph, enl, enh);
#pragma unroll
      for (int ct = 0; ct < 4; ++ct)
        acc[ct] = __builtin_amdgcn_mfma_f32_16x16x32_bf16(af, Bc[ct], acc[ct], 0, 0, 0);
      accd = __builtin_amdgcn_mfma_f32_16x16x32_bf16(af, ones, accd, 0, 0, 0);
      if (s < 63) {
#pragma unroll
        for (int ct = 0; ct < 4; ++ct) Bc[ct] = Bn[ct];
      }
    }
  }

  // epilogue: C row = q*4+r (both acc and accd), col = m
#pragma unroll
  for (int r = 0; r < 4; ++r) {
    float dinv = 1.0f / accd[r];
    size_t ob = ((size_t)(b * 2048 + i0 + w * 16 + q * 4 + r)) * 256 + f0;
#pragma unroll
    for (int ct = 0; ct < 4; ++ct) {
      float v = acc[ct][r] * dinv;
      v = v > 0.f ? v : (__expf(v) - 1.f);
      out[ob + ct * 16 + m] = v;
    }
  }
}

extern "C" void kernel_launch(void* const* d_in, const int* in_sizes, int n_in,
                              void* d_out, int out_size, void* d_ws, size_t ws_size,
                              hipStream_t stream) {
  const float* h   = (const float*)d_in[0];   // [8,2048,512] f32
  const int*   adj = (const int*)d_in[1];     // [8,2048,2048] i32
  const float* W   = (const float*)d_in[2];   // [512,256] f32
  const float* a   = (const float*)d_in[3];   // [512,1] f32
  float* out = (float*)d_out;                 // [8,2048,256] f32

  char* ws = (char*)d_ws;
  unsigned short* WhT = (unsigned short*)ws;                  // 8 MB   [8][256][2048] bf16
  unsigned short* WT  = (unsigned short*)(ws + 8388608);      // 256 KB [256][512] bf16
  float* E1p = (float*)(ws + 8388608 + 262144);               // 64 KB each
  float* E1n = E1p + 16384;
  float* E2p = E1n + 16384;
  float* E2n = E2p + 16384;
  unsigned char* bm = (unsigned char*)(ws + 8388608 + 262144 + 4 * 65536);  // 4 MB

  k_wt<<<dim3(64), dim3(256), 0, stream>>>(W, WT);
  k_pack<<<dim3(2048), dim3(256), 0, stream>>>(adj, bm);
  k_gemm1<<<dim3(1024), dim3(256), 0, stream>>>(h, WT, a, WhT, E1p, E1n, E2p, E2n);
  k_gat<<<dim3(1024), dim3(256), 0, stream>>>(bm, WhT, E1p, E1n, E2p, E2n, out);
}

// Round 7
// 350.219 us; speedup vs baseline: 1.1594x; 1.1594x over previous
//
#include <hip/hip_runtime.h>
#include <hip/hip_bf16.h>

#define GAT_ALPHA 0.2f

typedef short bf16x8 __attribute__((ext_vector_type(8)));
typedef float f32x4 __attribute__((ext_vector_type(4)));

__device__ __forceinline__ unsigned f2bf_u(float x) {
  union { float f; unsigned u; } v; v.f = x;
  return (v.u + 0x7fffu + ((v.u >> 16) & 1u)) >> 16;  // RNE to bf16
}
__device__ __forceinline__ unsigned short f2bf(float x) { return (unsigned short)f2bf_u(x); }

// ---------------- kernel 0: W (512x256 f32) -> WT bf16 (256x512) ----------
__global__ void k_wt(const float* __restrict__ W, unsigned short* __restrict__ WT) {
  int kb = blockIdx.x * 8;
  int f = threadIdx.x;
  bf16x8 o;
#pragma unroll
  for (int i = 0; i < 8; ++i) o[i] = (short)f2bf(W[(kb + i) * 256 + f]);
  *reinterpret_cast<bf16x8*>(WT + f * 512 + kb) = o;
}

// ---------------- fat kernel: adj->bitmap pack  +  gemm1 (h@W)^T ----------
// Roles interleaved so both HBM streams (adj 128 MB, h 64 MB) overlap.
//
// pack: per row, byte-col j8 stored at (j8&3)*64 + (j8>>2): k_gat lane q's
// bytes for ksteps s=0..63 are contiguous at q*64 (uint4 per 16-kstep group).
//
// gemm1 writes WhS in MFMA B-FRAGMENT layout:
//   WhS[b][ft(16)][s(64)][lane(64)][elem(8)] shorts
//   element (f, j): ft=f>>4, s=j>>5, lane=(f&15)+16*((j>>3)&3), elem=j&7
// so k_gat's B-load is base + lane*16B: one contiguous 1 KB per instruction.
__global__ __launch_bounds__(256, 4) void k_stage(
    const int* __restrict__ adj, unsigned char* __restrict__ bm,
    const float* __restrict__ h, const unsigned short* __restrict__ WT,
    const float* __restrict__ avec, unsigned short* __restrict__ WhS,
    float* __restrict__ E1p, float* __restrict__ E1n,
    float* __restrict__ E2p, float* __restrict__ E2n)
{
  const int bx = blockIdx.x, t = threadIdx.x;
  __shared__ __align__(16) unsigned short Wt[256 * 24];  // 12 KB (gemm1); pack reuses

  if (bx % 3 != 2) {
    // ---- pack role: 2048 virtual blocks, 8 rows each ----
    const int pid = (bx / 3) * 2 + (bx % 3);
    unsigned char* sb = reinterpret_cast<unsigned char*>(Wt);
    const int4* base = reinterpret_cast<const int4*>(adj + (size_t)pid * 8 * 2048);
#pragma unroll
    for (int i = 0; i < 8; ++i) {
      int4 v0 = base[i * 512 + t * 2];
      int4 v1 = base[i * 512 + t * 2 + 1];
      unsigned by = (v0.x != 0)        | ((v0.y != 0) << 1) | ((v0.z != 0) << 2) |
                    ((v0.w != 0) << 3) | ((v1.x != 0) << 4) | ((v1.y != 0) << 5) |
                    ((v1.z != 0) << 6) | ((v1.w != 0) << 7);
      sb[i * 256 + (t & 3) * 64 + (t >> 2)] = (unsigned char)by;
    }
    __syncthreads();
    reinterpret_cast<uint2*>(bm + (size_t)pid * 2048)[t] =
        reinterpret_cast<const uint2*>(sb)[t];
    return;
  }

  // ---- gemm1 role: 1024 virtual blocks = 8 b x 128 node-groups of 16 ----
  const int gid = bx / 3;
  const int b = gid & 7, ng = gid >> 3;
  const int n0 = ng * 16;
  const int lane = t & 63, w = t >> 6;
  const int l15 = lane & 15, q = lane >> 4;

  __shared__ float f1a[16], f2a[16];
  if (t < 16) { f1a[t] = 0.f; f2a[t] = 0.f; }

  f32x4 acc[4];
#pragma unroll
  for (int i = 0; i < 4; ++i) acc[i] = (f32x4){0.f, 0.f, 0.f, 0.f};

  const unsigned short* wtb = WT + (w * 64 + l15) * 512 + q * 8;
  const float* hrow = h + ((size_t)(b * 2048 + n0 + l15)) * 512 + q * 8;

  float4 hS0[2], hS1[2], hS2[2];
  hS0[0] = *reinterpret_cast<const float4*>(hrow);
  hS0[1] = *reinterpret_cast<const float4*>(hrow + 4);
  hS1[0] = *reinterpret_cast<const float4*>(hrow + 32);
  hS1[1] = *reinterpret_cast<const float4*>(hrow + 36);
  hS2[0] = *reinterpret_cast<const float4*>(hrow + 64);
  hS2[1] = *reinterpret_cast<const float4*>(hrow + 68);

#pragma unroll
  for (int k = 0; k < 16; ++k) {
    bf16x8 af[4];
#pragma unroll
    for (int mt = 0; mt < 4; ++mt)
      af[mt] = *reinterpret_cast<const bf16x8*>(wtb + mt * 16 * 512 + k * 32);
    float4 hN[2];
    if (k < 13) {
      hN[0] = *reinterpret_cast<const float4*>(hrow + (k + 3) * 32);
      hN[1] = *reinterpret_cast<const float4*>(hrow + (k + 3) * 32 + 4);
    }
    bf16x8 bb;
    {
      float4 x0 = hS0[0], x1 = hS0[1];
      bb[0] = (short)f2bf(x0.x); bb[1] = (short)f2bf(x0.y);
      bb[2] = (short)f2bf(x0.z); bb[3] = (short)f2bf(x0.w);
      bb[4] = (short)f2bf(x1.x); bb[5] = (short)f2bf(x1.y);
      bb[6] = (short)f2bf(x1.z); bb[7] = (short)f2bf(x1.w);
    }
#pragma unroll
    for (int mt = 0; mt < 4; ++mt)
      acc[mt] = __builtin_amdgcn_mfma_f32_16x16x32_bf16(af[mt], bb, acc[mt], 0, 0, 0);
    hS0[0] = hS1[0]; hS0[1] = hS1[1];
    hS1[0] = hS2[0]; hS1[1] = hS2[1];
    if (k < 13) { hS2[0] = hN[0]; hS2[1] = hN[1]; }
  }

  float s1 = 0.f, s2 = 0.f;
#pragma unroll
  for (int mt = 0; mt < 4; ++mt) {
#pragma unroll
    for (int r = 0; r < 4; ++r) {
      int f = w * 64 + mt * 16 + q * 4 + r;
      float v = acc[mt][r];
      Wt[f * 24 + l15] = f2bf(v);
      s1 += v * avec[f];
      s2 += v * avec[256 + f];
    }
  }
  s1 += __shfl_xor(s1, 16); s1 += __shfl_xor(s1, 32);
  s2 += __shfl_xor(s2, 16); s2 += __shfl_xor(s2, 32);
  __syncthreads();
  if (q == 0) {
    atomicAdd(&f1a[l15], s1);
    atomicAdd(&f2a[l15], s2);
  }
  // swizzled WhS store: thread t = f-row; two uint4 (8 j's each), coalesced
  {
    const int f = t, ft = f >> 4, s = ng >> 1;
    const size_t base = (size_t)b * 524288 + (size_t)ft * 32768 + (size_t)s * 512;
#pragma unroll
    for (int jj8 = 0; jj8 < 2; ++jj8) {
      int l = (f & 15) + 16 * ((ng * 2 + jj8) & 3);
      uint4 v = *reinterpret_cast<const uint4*>(Wt + f * 24 + jj8 * 8);
      *reinterpret_cast<uint4*>(WhS + base + l * 8) = v;
    }
  }
  __syncthreads();
  if (t < 16) {
    int n = b * 2048 + n0 + t;
    float f1 = f1a[t], f2 = f2a[t];
    E1p[n] = __expf(f1);
    E1n[n] = __expf(GAT_ALPHA * f1);
    E2p[n] = __expf(f2);
    E2n[n] = __expf(GAT_ALPHA * f2);
  }
}

// build one MFMA A-fragment (8 k-cols of one row) from a mask byte
__device__ __forceinline__ bf16x8 build_frag_r(
    unsigned by, float e1p, float e1n,
    float4 epl, float4 eph, float4 enl, float4 enh)
{
  float p0 = (by & 1u)   ? fmaxf(e1p * epl.x, e1n * enl.x) : 0.f;
  float p1 = (by & 2u)   ? fmaxf(e1p * epl.y, e1n * enl.y) : 0.f;
  float p2 = (by & 4u)   ? fmaxf(e1p * epl.z, e1n * enl.z) : 0.f;
  float p3 = (by & 8u)   ? fmaxf(e1p * epl.w, e1n * enl.w) : 0.f;
  float p4 = (by & 16u)  ? fmaxf(e1p * eph.x, e1n * enh.x) : 0.f;
  float p5 = (by & 32u)  ? fmaxf(e1p * eph.y, e1n * enh.y) : 0.f;
  float p6 = (by & 64u)  ? fmaxf(e1p * eph.z, e1n * enh.z) : 0.f;
  float p7 = (by & 128u) ? fmaxf(e1p * eph.w, e1n * enh.w) : 0.f;
  union { unsigned u[4]; bf16x8 v; } pk;
  pk.u[0] = f2bf_u(p0) | (f2bf_u(p1) << 16);
  pk.u[1] = f2bf_u(p2) | (f2bf_u(p3) << 16);
  pk.u[2] = f2bf_u(p4) | (f2bf_u(p5) << 16);
  pk.u[3] = f2bf_u(p6) | (f2bf_u(p7) << 16);
  return pk.v;
}

// ---------------- kernel 2: out = elu(softmax-masked P @ Wh) --------------
// BARRIER-FREE. Grid 512 = 8 b x 4 fg x 16 rg; 256 thr = 4 waves of
// 32 rows x 64 f (2 A-frags, 10 MFMAs/kstep). B-loads are contiguous 1 KB
// from fragment-swizzled WhS; masks reload per 16-kstep group (prefetched);
// den via ones-B MFMA. Stray s=63 prefetches land inside d_ws (harmless).
__global__ __launch_bounds__(256, 2) void k_gat(
    const unsigned char* __restrict__ bm, const unsigned short* __restrict__ WhS,
    const float* __restrict__ E1p, const float* __restrict__ E1n,
    const float* __restrict__ E2p, const float* __restrict__ E2n,
    float* __restrict__ out)
{
  const int bx = blockIdx.x;
  const int b = bx & 7, fg = (bx >> 3) & 3, rg = bx >> 5;
  const int t = threadIdx.x, lane = t & 63, w = t >> 6;
  const int m = lane & 15, q = lane >> 4;
  const int row0 = rg * 128 + w * 32 + m, row1 = row0 + 16;
  const int f0 = fg * 64;

  const unsigned char* bmr0 = bm + ((size_t)(b * 2048 + row0)) * 256 + q * 64;
  const unsigned char* bmr1 = bmr0 + 16 * 256;
  const float e1p0 = E1p[b * 2048 + row0], e1n0 = E1n[b * 2048 + row0];
  const float e1p1 = E1p[b * 2048 + row1], e1n1 = E1n[b * 2048 + row1];
  const int e2b = b * 2048 + q * 8;
  const unsigned short* Wb = WhS + (size_t)b * 524288 + (size_t)(fg * 4) * 32768 + lane * 8;

  bf16x8 ones;
#pragma unroll
  for (int i = 0; i < 8; ++i) ones[i] = (short)0x3F80;

  f32x4 acc0[4], acc1[4], accd0, accd1;
#pragma unroll
  for (int i = 0; i < 4; ++i) {
    acc0[i] = (f32x4){0.f, 0.f, 0.f, 0.f};
    acc1[i] = (f32x4){0.f, 0.f, 0.f, 0.f};
  }
  accd0 = (f32x4){0.f, 0.f, 0.f, 0.f};
  accd1 = (f32x4){0.f, 0.f, 0.f, 0.f};

  // prologue: masks(g0), B(0), e2(0)
  uint4 cur0 = *reinterpret_cast<const uint4*>(bmr0);
  uint4 cur1 = *reinterpret_cast<const uint4*>(bmr1);
  bf16x8 Bc[4];
#pragma unroll
  for (int ct = 0; ct < 4; ++ct)
    Bc[ct] = *reinterpret_cast<const bf16x8*>(Wb + ct * 32768);
  float4 pA = *reinterpret_cast<const float4*>(E2p + e2b);
  float4 pB = *reinterpret_cast<const float4*>(E2p + e2b + 4);
  float4 nA = *reinterpret_cast<const float4*>(E2n + e2b);
  float4 nB = *reinterpret_cast<const float4*>(E2n + e2b + 4);

  for (int g = 0; g < 4; ++g) {
    // prefetch next group's masks (full 16-kstep lead)
    uint4 nxt0 = *reinterpret_cast<const uint4*>(bmr0 + (g + 1) * 16);
    uint4 nxt1 = *reinterpret_cast<const uint4*>(bmr1 + (g + 1) * 16);
#pragma unroll
    for (int s2 = 0; s2 < 16; ++s2) {
      const int s = g * 16 + s2;
      // prefetch B(s+1), e2(s+1) — consumed next kstep
      bf16x8 Bn[4];
#pragma unroll
      for (int ct = 0; ct < 4; ++ct)
        Bn[ct] = *reinterpret_cast<const bf16x8*>(Wb + ct * 32768 + (s + 1) * 512);
      float4 qpA = *reinterpret_cast<const float4*>(E2p + e2b + (s + 1) * 32);
      float4 qpB = *reinterpret_cast<const float4*>(E2p + e2b + (s + 1) * 32 + 4);
      float4 qnA = *reinterpret_cast<const float4*>(E2n + e2b + (s + 1) * 32);
      float4 qnB = *reinterpret_cast<const float4*>(E2n + e2b + (s + 1) * 32 + 4);
      // extract mask bytes (static word/shift under unroll)
      unsigned bw0 = (s2 >> 2) == 0 ? cur0.x : (s2 >> 2) == 1 ? cur0.y
                   : (s2 >> 2) == 2 ? cur0.z : cur0.w;
      unsigned bw1 = (s2 >> 2) == 0 ? cur1.x : (s2 >> 2) == 1 ? cur1.y
                   : (s2 >> 2) == 2 ? cur1.z : cur1.w;
      unsigned by0 = (bw0 >> ((s2 & 3) * 8)) & 0xffu;
      unsigned by1 = (bw1 >> ((s2 & 3) * 8)) & 0xffu;
      // build A-frags in registers, 10 MFMAs
      bf16x8 af0 = build_frag_r(by0, e1p0, e1n0, pA, pB, nA, nB);
      bf16x8 af1 = build_frag_r(by1, e1p1, e1n1, pA, pB, nA, nB);
#pragma unroll
      for (int ct = 0; ct < 4; ++ct)
        acc0[ct] = __builtin_amdgcn_mfma_f32_16x16x32_bf16(af0, Bc[ct], acc0[ct], 0, 0, 0);
      accd0 = __builtin_amdgcn_mfma_f32_16x16x32_bf16(af0, ones, accd0, 0, 0, 0);
#pragma unroll
      for (int ct = 0; ct < 4; ++ct)
        acc1[ct] = __builtin_amdgcn_mfma_f32_16x16x32_bf16(af1, Bc[ct], acc1[ct], 0, 0, 0);
      accd1 = __builtin_amdgcn_mfma_f32_16x16x32_bf16(af1, ones, accd1, 0, 0, 0);
      // rotate (renamed by unroll)
#pragma unroll
      for (int ct = 0; ct < 4; ++ct) Bc[ct] = Bn[ct];
      pA = qpA; pB = qpB; nA = qnA; nB = qnB;
    }
    cur0 = nxt0; cur1 = nxt1;
  }

  // epilogue: C row = q*4+r, col = m; den rows match acc rows
#pragma unroll
  for (int r = 0; r < 4; ++r) {
    float di0 = 1.0f / accd0[r];
    float di1 = 1.0f / accd1[r];
    size_t ob0 = ((size_t)(b * 2048 + rg * 128 + w * 32 + q * 4 + r)) * 256 + f0;
    size_t ob1 = ob0 + (size_t)16 * 256;
#pragma unroll
    for (int ct = 0; ct < 4; ++ct) {
      float v0 = acc0[ct][r] * di0;
      v0 = v0 > 0.f ? v0 : (__expf(v0) - 1.f);
      out[ob0 + ct * 16 + m] = v0;
      float v1 = acc1[ct][r] * di1;
      v1 = v1 > 0.f ? v1 : (__expf(v1) - 1.f);
      out[ob1 + ct * 16 + m] = v1;
    }
  }
}

extern "C" void kernel_launch(void* const* d_in, const int* in_sizes, int n_in,
                              void* d_out, int out_size, void* d_ws, size_t ws_size,
                              hipStream_t stream) {
  const float* h   = (const float*)d_in[0];   // [8,2048,512] f32
  const int*   adj = (const int*)d_in[1];     // [8,2048,2048] i32
  const float* W   = (const float*)d_in[2];   // [512,256] f32
  const float* a   = (const float*)d_in[3];   // [512,1] f32
  float* out = (float*)d_out;                 // [8,2048,256] f32

  char* ws = (char*)d_ws;
  unsigned short* WhS = (unsigned short*)ws;                  // 8 MB fragment-swizzled
  unsigned short* WT  = (unsigned short*)(ws + 8388608);      // 256 KB
  float* E1p = (float*)(ws + 8388608 + 262144);               // 64 KB each
  float* E1n = E1p + 16384;
  float* E2p = E1n + 16384;
  float* E2n = E2p + 16384;
  unsigned char* bm = (unsigned char*)(ws + 8388608 + 262144 + 4 * 65536);  // 4 MB

  k_wt<<<dim3(64), dim3(256), 0, stream>>>(W, WT);
  k_stage<<<dim3(3072), dim3(256), 0, stream>>>(adj, bm, h, WT, a, WhS,
                                                E1p, E1n, E2p, E2n);
  k_gat<<<dim3(512), dim3(256), 0, stream>>>(bm, WhS, E1p, E1n, E2p, E2n, out);
}

// Round 8
// 331.795 us; speedup vs baseline: 1.2238x; 1.0555x over previous
//
#include <hip/hip_runtime.h>
#include <hip/hip_bf16.h>

#define GAT_ALPHA 0.2f

typedef short bf16x8 __attribute__((ext_vector_type(8)));
typedef float f32x4 __attribute__((ext_vector_type(4)));

__device__ __forceinline__ unsigned f2bf_u(float x) {
  union { float f; unsigned u; } v; v.f = x;
  return (v.u + 0x7fffu + ((v.u >> 16) & 1u)) >> 16;  // RNE to bf16
}
__device__ __forceinline__ unsigned short f2bf(float x) { return (unsigned short)f2bf_u(x); }

// ---------------- kernel 0: W (512x256 f32) -> WTS, A-fragment swizzled ---
// WTS[ft(16)][s(16)][lane(64)][elem(8)]: element (f,k) at ft=f>>4,
// s=k>>5, lane=(f&15)+16*((k>>3)&3), elem=k&7. A gemm1 af-load is then
// base + lane*16B: one contiguous 1 KB per instruction.
__global__ void k_wt(const float* __restrict__ W, unsigned short* __restrict__ WTS) {
  int kb = blockIdx.x * 8;       // 64 blocks, 8 consecutive k each
  int f = threadIdx.x;           // 256 threads = one f each
  bf16x8 o;
#pragma unroll
  for (int i = 0; i < 8; ++i) o[i] = (short)f2bf(W[(kb + i) * 256 + f]);
  const int ft = f >> 4, s = kb >> 5, q = (kb >> 3) & 3;
  const int lane = (f & 15) + 16 * q;
  *reinterpret_cast<bf16x8*>(WTS + ((ft * 16 + s) * 64 + lane) * 8) = o;
}

// ---------------- kernel P: adj (int32 0/1) -> permuted bitmap ------------
// Per row, byte-col j8 at (j8&3)*64 + (j8>>2): k_gat lane q's bytes for
// ksteps s=0..63 are contiguous at q*64. Grid 2048 x 256 thr = 8 rows.
__global__ __launch_bounds__(256) void k_pack(const int* __restrict__ adj,
                                              unsigned char* __restrict__ bm) {
  __shared__ unsigned char sb[2048];
  const int bId = blockIdx.x, t = threadIdx.x;
  const int4* base = reinterpret_cast<const int4*>(adj + (size_t)bId * 8 * 2048);
#pragma unroll
  for (int i = 0; i < 8; ++i) {
    int4 v0 = base[i * 512 + t * 2];
    int4 v1 = base[i * 512 + t * 2 + 1];
    unsigned by = (v0.x != 0)        | ((v0.y != 0) << 1) | ((v0.z != 0) << 2) |
                  ((v0.w != 0) << 3) | ((v1.x != 0) << 4) | ((v1.y != 0) << 5) |
                  ((v1.z != 0) << 6) | ((v1.w != 0) << 7);
    sb[i * 256 + (t & 3) * 64 + (t >> 2)] = (unsigned char)by;
  }
  __syncthreads();
  reinterpret_cast<uint2*>(bm + (size_t)bId * 2048)[t] =
      reinterpret_cast<const uint2*>(sb)[t];
}

// ---------------- kernel 1: WhS = swizzled (h@W)^T bf16, + exp(f1/f2) -----
// Grid 1024 (8 b x 128 node-groups of 16), 256 thr, 4 blocks/CU.
// af loads contiguous from WTS (depth-1 prefetch); h depth-3 pipeline.
// WhS[b][ft(16)][s(64)][lane(64)][elem(8)]: element (f,j) at ft=f>>4,
// s=j>>5, lane=(f&15)+16*((j>>3)&3), elem=j&7.
__global__ __launch_bounds__(256, 4) void k_gemm1(
    const float* __restrict__ h, const unsigned short* __restrict__ WTS,
    const float* __restrict__ avec, unsigned short* __restrict__ WhS,
    float* __restrict__ E1p, float* __restrict__ E1n,
    float* __restrict__ E2p, float* __restrict__ E2n)
{
  const int bx = blockIdx.x;
  const int b = bx & 7, ng = bx >> 3;
  const int n0 = ng * 16;
  const int t = threadIdx.x;
  const int lane = t & 63, w = t >> 6;
  const int l15 = lane & 15, q = lane >> 4;

  __shared__ __align__(16) unsigned short Wt[256 * 24];
  __shared__ float f1a[16], f2a[16];
  if (t < 16) { f1a[t] = 0.f; f2a[t] = 0.f; }

  f32x4 acc[4];
#pragma unroll
  for (int i = 0; i < 4; ++i) acc[i] = (f32x4){0.f, 0.f, 0.f, 0.f};

  // af fragment base for this wave: ft = w*4 + mt, address contiguous in lane
  const unsigned short* wts = WTS + (size_t)(w * 4) * 8192 + lane * 8;
  const float* hrow = h + ((size_t)(b * 2048 + n0 + l15)) * 512 + q * 8;

  // prologue: af(0), h(0..2)
  bf16x8 afA[4], afN[4];
#pragma unroll
  for (int mt = 0; mt < 4; ++mt)
    afA[mt] = *reinterpret_cast<const bf16x8*>(wts + mt * 8192);
  float4 hS0[2], hS1[2], hS2[2];
  hS0[0] = *reinterpret_cast<const float4*>(hrow);
  hS0[1] = *reinterpret_cast<const float4*>(hrow + 4);
  hS1[0] = *reinterpret_cast<const float4*>(hrow + 32);
  hS1[1] = *reinterpret_cast<const float4*>(hrow + 36);
  hS2[0] = *reinterpret_cast<const float4*>(hrow + 64);
  hS2[1] = *reinterpret_cast<const float4*>(hrow + 68);

#pragma unroll
  for (int k = 0; k < 16; ++k) {
    // issue af(k+1) — contiguous 1 KB per instruction, L2-resident
    if (k < 15) {
#pragma unroll
      for (int mt = 0; mt < 4; ++mt)
        afN[mt] = *reinterpret_cast<const bf16x8*>(wts + mt * 8192 + (k + 1) * 512);
    }
    // issue h(k+3)
    float4 hN[2];
    if (k < 13) {
      hN[0] = *reinterpret_cast<const float4*>(hrow + (k + 3) * 32);
      hN[1] = *reinterpret_cast<const float4*>(hrow + (k + 3) * 32 + 4);
    }
    bf16x8 bb;
    {
      float4 x0 = hS0[0], x1 = hS0[1];
      bb[0] = (short)f2bf(x0.x); bb[1] = (short)f2bf(x0.y);
      bb[2] = (short)f2bf(x0.z); bb[3] = (short)f2bf(x0.w);
      bb[4] = (short)f2bf(x1.x); bb[5] = (short)f2bf(x1.y);
      bb[6] = (short)f2bf(x1.z); bb[7] = (short)f2bf(x1.w);
    }
#pragma unroll
    for (int mt = 0; mt < 4; ++mt)
      acc[mt] = __builtin_amdgcn_mfma_f32_16x16x32_bf16(afA[mt], bb, acc[mt], 0, 0, 0);
    // rotate
    if (k < 15) {
#pragma unroll
      for (int mt = 0; mt < 4; ++mt) afA[mt] = afN[mt];
    }
    hS0[0] = hS1[0]; hS0[1] = hS1[1];
    hS1[0] = hS2[0]; hS1[1] = hS2[1];
    if (k < 13) { hS2[0] = hN[0]; hS2[1] = hN[1]; }
  }

  float s1 = 0.f, s2 = 0.f;
#pragma unroll
  for (int mt = 0; mt < 4; ++mt) {
#pragma unroll
    for (int r = 0; r < 4; ++r) {
      int f = w * 64 + mt * 16 + q * 4 + r;
      float v = acc[mt][r];
      Wt[f * 24 + l15] = f2bf(v);
      s1 += v * avec[f];
      s2 += v * avec[256 + f];
    }
  }
  s1 += __shfl_xor(s1, 16); s1 += __shfl_xor(s1, 32);
  s2 += __shfl_xor(s2, 16); s2 += __shfl_xor(s2, 32);
  __syncthreads();
  if (q == 0) {
    atomicAdd(&f1a[l15], s1);
    atomicAdd(&f2a[l15], s2);
  }
  // swizzled WhS store: thread t = f-row; two uint4 (8 j's each)
  {
    const int f = t, ft = f >> 4, s = ng >> 1;
    const size_t base = (size_t)b * 524288 + (size_t)ft * 32768 + (size_t)s * 512;
#pragma unroll
    for (int jj8 = 0; jj8 < 2; ++jj8) {
      int l = (f & 15) + 16 * ((ng * 2 + jj8) & 3);
      uint4 v = *reinterpret_cast<const uint4*>(Wt + f * 24 + jj8 * 8);
      *reinterpret_cast<uint4*>(WhS + base + l * 8) = v;
    }
  }
  __syncthreads();
  if (t < 16) {
    int n = b * 2048 + n0 + t;
    float f1 = f1a[t], f2 = f2a[t];
    E1p[n] = __expf(f1);
    E1n[n] = __expf(GAT_ALPHA * f1);
    E2p[n] = __expf(f2);
    E2n[n] = __expf(GAT_ALPHA * f2);
  }
}

// build one MFMA A-fragment (8 k-cols of one row) from a mask byte
__device__ __forceinline__ bf16x8 build_frag_r(
    unsigned by, float e1p, float e1n,
    float4 epl, float4 eph, float4 enl, float4 enh)
{
  float p0 = (by & 1u)   ? fmaxf(e1p * epl.x, e1n * enl.x) : 0.f;
  float p1 = (by & 2u)   ? fmaxf(e1p * epl.y, e1n * enl.y) : 0.f;
  float p2 = (by & 4u)   ? fmaxf(e1p * epl.z, e1n * enl.z) : 0.f;
  float p3 = (by & 8u)   ? fmaxf(e1p * epl.w, e1n * enl.w) : 0.f;
  float p4 = (by & 16u)  ? fmaxf(e1p * eph.x, e1n * enh.x) : 0.f;
  float p5 = (by & 32u)  ? fmaxf(e1p * eph.y, e1n * enh.y) : 0.f;
  float p6 = (by & 64u)  ? fmaxf(e1p * eph.z, e1n * enh.z) : 0.f;
  float p7 = (by & 128u) ? fmaxf(e1p * eph.w, e1n * enh.w) : 0.f;
  union { unsigned u[4]; bf16x8 v; } pk;
  pk.u[0] = f2bf_u(p0) | (f2bf_u(p1) << 16);
  pk.u[1] = f2bf_u(p2) | (f2bf_u(p3) << 16);
  pk.u[2] = f2bf_u(p4) | (f2bf_u(p5) << 16);
  pk.u[3] = f2bf_u(p6) | (f2bf_u(p7) << 16);
  return pk.v;
}

// ---------------- kernel 2: out = elu(softmax-masked P @ Wh) --------------
// BARRIER-FREE. Grid 1024 = 8 b x 4 fg x 32 rg; 256 thr = 4 waves of
// 16 rows x 64 f (1 A-frag, 5 MFMAs/kstep). B-loads contiguous 1 KB from
// WhS (depth-1), e2 depth-1, masks prefetched a 16-kstep group ahead.
// den via ones-B MFMA (C-layout rows match numerator). (256,3): no spill.
__global__ __launch_bounds__(256, 3) void k_gat(
    const unsigned char* __restrict__ bm, const unsigned short* __restrict__ WhS,
    const float* __restrict__ E1p, const float* __restrict__ E1n,
    const float* __restrict__ E2p, const float* __restrict__ E2n,
    float* __restrict__ out)
{
  const int bx = blockIdx.x;
  const int b = bx & 7, fg = (bx >> 3) & 3, rg = bx >> 5;
  const int t = threadIdx.x, lane = t & 63, w = t >> 6;
  const int m = lane & 15, q = lane >> 4;
  const int row = rg * 64 + w * 16 + m;
  const int f0 = fg * 64;

  const unsigned char* bmr = bm + ((size_t)(b * 2048 + row)) * 256 + q * 64;
  const float e1p = E1p[b * 2048 + row], e1n = E1n[b * 2048 + row];
  const int e2b = b * 2048 + q * 8;
  const unsigned short* Wb = WhS + (size_t)b * 524288 + (size_t)(fg * 4) * 32768 + lane * 8;

  bf16x8 ones;
#pragma unroll
  for (int i = 0; i < 8; ++i) ones[i] = (short)0x3F80;

  f32x4 acc[4], accd;
#pragma unroll
  for (int i = 0; i < 4; ++i) acc[i] = (f32x4){0.f, 0.f, 0.f, 0.f};
  accd = (f32x4){0.f, 0.f, 0.f, 0.f};

  // prologue: masks(g0), B(0), e2(0)
  uint4 cur = *reinterpret_cast<const uint4*>(bmr);
  bf16x8 Bc[4];
#pragma unroll
  for (int ct = 0; ct < 4; ++ct)
    Bc[ct] = *reinterpret_cast<const bf16x8*>(Wb + ct * 32768);
  float4 pA = *reinterpret_cast<const float4*>(E2p + e2b);
  float4 pB = *reinterpret_cast<const float4*>(E2p + e2b + 4);
  float4 nA = *reinterpret_cast<const float4*>(E2n + e2b);
  float4 nB = *reinterpret_cast<const float4*>(E2n + e2b + 4);

  for (int g = 0; g < 4; ++g) {
    uint4 nxt = *reinterpret_cast<const uint4*>(bmr + (g + 1) * 16);  // group lead
#pragma unroll
    for (int s2 = 0; s2 < 16; ++s2) {
      const int s = g * 16 + s2;
      // prefetch B(s+1), e2(s+1)
      bf16x8 Bn[4];
#pragma unroll
      for (int ct = 0; ct < 4; ++ct)
        Bn[ct] = *reinterpret_cast<const bf16x8*>(Wb + ct * 32768 + (s + 1) * 512);
      float4 qpA = *reinterpret_cast<const float4*>(E2p + e2b + (s + 1) * 32);
      float4 qpB = *reinterpret_cast<const float4*>(E2p + e2b + (s + 1) * 32 + 4);
      float4 qnA = *reinterpret_cast<const float4*>(E2n + e2b + (s + 1) * 32);
      float4 qnB = *reinterpret_cast<const float4*>(E2n + e2b + (s + 1) * 32 + 4);
      // mask byte (static word/shift under unroll)
      unsigned bw = (s2 >> 2) == 0 ? cur.x : (s2 >> 2) == 1 ? cur.y
                  : (s2 >> 2) == 2 ? cur.z : cur.w;
      unsigned by = (bw >> ((s2 & 3) * 8)) & 0xffu;
      // build A-frag, 5 MFMAs
      bf16x8 af = build_frag_r(by, e1p, e1n, pA, pB, nA, nB);
#pragma unroll
      for (int ct = 0; ct < 4; ++ct)
        acc[ct] = __builtin_amdgcn_mfma_f32_16x16x32_bf16(af, Bc[ct], acc[ct], 0, 0, 0);
      accd = __builtin_amdgcn_mfma_f32_16x16x32_bf16(af, ones, accd, 0, 0, 0);
      // rotate (renamed by unroll)
#pragma unroll
      for (int ct = 0; ct < 4; ++ct) Bc[ct] = Bn[ct];
      pA = qpA; pB = qpB; nA = qnA; nB = qnB;
    }
    cur = nxt;
  }

  // epilogue: C row = q*4+r, col = m; accd rows match
#pragma unroll
  for (int r = 0; r < 4; ++r) {
    float dinv = 1.0f / accd[r];
    size_t ob = ((size_t)(b * 2048 + rg * 64 + w * 16 + q * 4 + r)) * 256 + f0;
#pragma unroll
    for (int ct = 0; ct < 4; ++ct) {
      float v = acc[ct][r] * dinv;
      v = v > 0.f ? v : (__expf(v) - 1.f);
      out[ob + ct * 16 + m] = v;
    }
  }
}

extern "C" void kernel_launch(void* const* d_in, const int* in_sizes, int n_in,
                              void* d_out, int out_size, void* d_ws, size_t ws_size,
                              hipStream_t stream) {
  const float* h   = (const float*)d_in[0];   // [8,2048,512] f32
  const int*   adj = (const int*)d_in[1];     // [8,2048,2048] i32
  const float* W   = (const float*)d_in[2];   // [512,256] f32
  const float* a   = (const float*)d_in[3];   // [512,1] f32
  float* out = (float*)d_out;                 // [8,2048,256] f32

  char* ws = (char*)d_ws;
  unsigned short* WhS = (unsigned short*)ws;                  // 8 MB fragment-swizzled
  unsigned short* WTS = (unsigned short*)(ws + 8388608);      // 256 KB fragment-swizzled
  float* E1p = (float*)(ws + 8388608 + 262144);               // 64 KB each
  float* E1n = E1p + 16384;
  float* E2p = E1n + 16384;
  float* E2n = E2p + 16384;
  unsigned char* bm = (unsigned char*)(ws + 8388608 + 262144 + 4 * 65536);  // 4 MB

  k_wt<<<dim3(64), dim3(256), 0, stream>>>(W, WTS);
  k_pack<<<dim3(2048), dim3(256), 0, stream>>>(adj, bm);
  k_gemm1<<<dim3(1024), dim3(256), 0, stream>>>(h, WTS, a, WhS, E1p, E1n, E2p, E2n);
  k_gat<<<dim3(1024), dim3(256), 0, stream>>>(bm, WhS, E1p, E1n, E2p, E2n, out);
}